// Round 3
// baseline (128.421 us; speedup 1.0000x reference)
//
#include <hip/hip_runtime.h>
#include <math.h>

// Lane = node, wave = output-column chunk. Activations live TRANSPOSED in LDS:
// X_t[feature][node], stride 65 (odd -> lift's 4-quarter writes are <=2-way,
// GEMM reads are lane-consecutive = conflict-free). Weights are wave-uniform
// (readfirstlane) -> scalar loads (K$) -> FMA with SGPR operand: no per-lane
// weight traffic at all.
constexpr int ST = 65;   // node stride of transposed LDS buffers

__global__ __launch_bounds__(256, 2)
void flatnet_fused(const float* __restrict__ pgi,
                   const float* __restrict__ Wl, const float* __restrict__ bl,
                   const float* __restrict__ Wc, const float* __restrict__ bc,
                   const float* __restrict__ W1, const float* __restrict__ b1,
                   const float* __restrict__ W2, const float* __restrict__ b2,
                   const float* __restrict__ W3, const float* __restrict__ b3,
                   const float* __restrict__ W4, const float* __restrict__ b4,
                   float* __restrict__ out)
{
    __shared__ float sA[96  * ST];  // V_t[96][64]  -> H1_t[64][64] -> H3_t[16][64]
    __shared__ float sB[128 * ST];  // C_t[128][64] -> H2_t[32][64]

    const int t    = threadIdx.x;
    const int blk  = blockIdx.x;
    const int lane = t & 63;
    const int wv   = __builtin_amdgcn_readfirstlane(t >> 6);  // 0..3, provably uniform

    // ===== Phase 0: lift (3->32) + ring-group max (pre-activation), leaky after =====
    // 4 threads/node, q = dim-quarter (8 dims), each thread scans all 64 points.
    {
        const int ln = t >> 2;          // local node 0..63
        const int q  = t & 3;           // dims q*8 .. q*8+7
        const int gn = blk * 64 + ln;   // global node = b*1024 + gi*32 + gj
        const int b  = gn >> 10;
        const int g  = gn & 1023;
        const int gi = g >> 5, gj = g & 31;

        float w0[8], w1[8], w2[8], bb[8];
        #pragma unroll
        for (int d = 0; d < 8; ++d) {
            const int dd = q * 8 + d;
            w0[d] = Wl[dd];
            w1[d] = Wl[32 + dd];
            w2[d] = Wl[64 + dd];
            bb[d] = bl[dd];
        }

        float gm[3][8];
        #pragma unroll
        for (int gg = 0; gg < 3; ++gg)
            #pragma unroll
            for (int d = 0; d < 8; ++d) gm[gg][d] = -INFINITY;

        // ring group of (row,col): 0=inner(d==3), 1=inter(d==2), 2=outer(d<2)
        constexpr int GT[8][8] = {
            {2,2,2,2,2,2,2,2},
            {2,2,2,2,2,2,2,2},
            {2,2,1,1,1,1,2,2},
            {2,2,1,0,0,1,2,2},
            {2,2,1,0,0,1,2,2},
            {2,2,1,1,1,1,2,2},
            {2,2,2,2,2,2,2,2},
            {2,2,2,2,2,2,2,2},
        };

        const size_t rowbase = (size_t)b * 65536 + ((size_t)gi * 8) * 256 + (size_t)gj * 8;
        #pragma unroll
        for (int pi = 0; pi < 8; ++pi) {
            const float4* src = (const float4*)(pgi + (rowbase + (size_t)pi * 256) * 3);
            float f[24];
            #pragma unroll
            for (int l = 0; l < 6; ++l) {
                const float4 v = src[l];
                f[l*4+0] = v.x; f[l*4+1] = v.y; f[l*4+2] = v.z; f[l*4+3] = v.w;
            }
            #pragma unroll
            for (int pj = 0; pj < 8; ++pj) {
                const int grp = GT[pi][pj];
                const float x = f[pj*3], y = f[pj*3+1], z = f[pj*3+2];
                #pragma unroll
                for (int d = 0; d < 8; ++d) {
                    float v = fmaf(x, w0[d], bb[d]);
                    v = fmaf(y, w1[d], v);
                    v = fmaf(z, w2[d], v);
                    gm[grp][d] = fmaxf(gm[grp][d], v);   // max BEFORE activation (monotone)
                }
            }
        }
        // leaky once per group value; V feature order = [inner|inter|outer], transposed store
        #pragma unroll
        for (int gg = 0; gg < 3; ++gg)
            #pragma unroll
            for (int d = 0; d < 8; ++d) {
                const float v = gm[gg][d];
                sA[(gg*32 + q*8 + d) * ST + ln] = fmaxf(v, 0.2f * v);
            }
    }
    __syncthreads();

    // ===== Phase 1: C = leaky(V @ Wc[96,128] + bc); wave wv -> cols 32wv..32wv+31 =====
    {
        const float* wp = Wc + (wv << 5);
        const float* bp = bc + (wv << 5);
        float acc[32];
        #pragma unroll
        for (int c = 0; c < 32; ++c) acc[c] = bp[c];           // uniform -> scalar bcast
        for (int j = 0; j < 96; ++j) {
            const float a = sA[j * ST + lane];                 // own node's value
            #pragma unroll
            for (int c = 0; c < 32; ++c)
                acc[c] = fmaf(a, wp[j*128 + c], acc[c]);       // weight = SGPR operand
        }
        #pragma unroll
        for (int c = 0; c < 32; ++c) {
            const float v = acc[c];
            sB[((wv << 5) + c) * ST + lane] = fmaxf(v, 0.2f * v);
        }
    }
    __syncthreads();

    // ===== Phase 2: H1 = relu(C @ W1[128,64] + b1); wave -> cols 16wv.. =====
    {
        const float* wp = W1 + (wv << 4);
        const float* bp = b1 + (wv << 4);
        float acc[16];
        #pragma unroll
        for (int c = 0; c < 16; ++c) acc[c] = bp[c];
        for (int j = 0; j < 128; ++j) {
            const float a = sB[j * ST + lane];
            #pragma unroll
            for (int c = 0; c < 16; ++c)
                acc[c] = fmaf(a, wp[j*64 + c], acc[c]);
        }
        #pragma unroll
        for (int c = 0; c < 16; ++c)
            sA[((wv << 4) + c) * ST + lane] = fmaxf(acc[c], 0.f);
    }
    __syncthreads();

    // ===== Phase 3: H2 = relu(H1 @ W2[64,32] + b2); wave -> cols 8wv.. =====
    {
        const float* wp = W2 + (wv << 3);
        const float* bp = b2 + (wv << 3);
        float acc[8];
        #pragma unroll
        for (int c = 0; c < 8; ++c) acc[c] = bp[c];
        for (int j = 0; j < 64; ++j) {
            const float a = sA[j * ST + lane];
            #pragma unroll
            for (int c = 0; c < 8; ++c)
                acc[c] = fmaf(a, wp[j*32 + c], acc[c]);
        }
        #pragma unroll
        for (int c = 0; c < 8; ++c)
            sB[((wv << 3) + c) * ST + lane] = fmaxf(acc[c], 0.f);
    }
    __syncthreads();

    // ===== Phase 4: H3 = relu(H2 @ W3[32,16] + b3); wave -> cols 4wv.. =====
    {
        const float* wp = W3 + (wv << 2);
        const float* bp = b3 + (wv << 2);
        float acc[4];
        #pragma unroll
        for (int c = 0; c < 4; ++c) acc[c] = bp[c];
        for (int j = 0; j < 32; ++j) {
            const float a = sB[j * ST + lane];
            #pragma unroll
            for (int c = 0; c < 4; ++c)
                acc[c] = fmaf(a, wp[j*16 + c], acc[c]);
        }
        #pragma unroll
        for (int c = 0; c < 4; ++c)
            sA[((wv << 2) + c) * ST + lane] = fmaxf(acc[c], 0.f);
    }
    __syncthreads();

    // ===== Phase 5: out = H3 @ W4[16,3] + b4; wave wv (<3) -> output col wv =====
    if (wv < 3) {                                  // uniform branch
        float acc = b4[wv];
        #pragma unroll
        for (int j = 0; j < 16; ++j)
            acc = fmaf(sA[j * ST + lane], W4[j*3 + wv], acc);
        out[((size_t)blk * 64 + lane) * 3 + wv] = acc;
    }
}

extern "C" void kernel_launch(void* const* d_in, const int* in_sizes, int n_in,
                              void* d_out, int out_size, void* d_ws, size_t ws_size,
                              hipStream_t stream)
{
    const float* pgi = (const float*)d_in[0];
    const float* Wl  = (const float*)d_in[1];
    const float* bl  = (const float*)d_in[2];
    const float* Wc  = (const float*)d_in[3];
    const float* bc  = (const float*)d_in[4];
    const float* W1  = (const float*)d_in[5];
    const float* b1  = (const float*)d_in[6];
    const float* W2  = (const float*)d_in[7];
    const float* b2  = (const float*)d_in[8];
    const float* W3  = (const float*)d_in[9];
    const float* b3  = (const float*)d_in[10];
    const float* W4  = (const float*)d_in[11];
    const float* b4  = (const float*)d_in[12];

    hipLaunchKernelGGL(flatnet_fused, dim3(512), dim3(256), 0, stream,
                       pgi, Wl, bl, Wc, bc, W1, b1, W2, b2, W3, b3, W4, b4,
                       (float*)d_out);
}